// Round 2
// baseline (588.092 us; speedup 1.0000x reference)
//
#include <hip/hip_runtime.h>
#include <math.h>

#define NB 16
#define NA 8400
#define NG 128
#define NC 5
#define KTOP 10
#define MAXF 5

// ---------- shared device math (must be bit-identical across kernels) ----------

static __device__ __forceinline__ double sigmoid_clip(double x) {
    double s = 1.0 / (1.0 + exp(-x));
    s = fmin(fmax(s, 1e-9), 1.0);
    return s;
}

// Full align-metric chain in f64, mirroring reference op order exactly.
static __device__ __forceinline__ void metric_chain(
    double s, double px, double py, double ax, double ay,
    double cx, double cy, double ct, double st,
    double scale, double w, double h, bool fb,
    double& am, double& ov)
{
    double dx = px - cx, dy = py - cy;
    double d  = sqrt(dx * dx + dy * dy);
    double r  = d / (scale + 1e-6);
    ov = exp(-(r * r));
    double am0 = exp(0.5 * log(s + 1e-9) + 6.0 * log(ov + 1e-9));
    double cdx = ax - cx, cdy = ay - cy;
    double cd  = sqrt(cdx * cdx + cdy * cdy);
    double cr  = cd / (scale * 1.5 + 1e-6);
    double cw  = exp(-(cr * cr));
    am0 *= cw;
    double ldx = cdx * ct - cdy * st;
    double ldy = cdx * st + cdy * ct;
    bool inb = (fabs(ldx) < w * 1.5) && (fabs(ldy) < h * 1.5);
    am = (inb || fb) ? am0 : 0.0;
}

// ---------- K1: per-gt fallback candidates ----------

__global__ __launch_bounds__(256) void k_fallback(
    const float* __restrict__ anchor_points,
    const float* __restrict__ gt_bboxes,
    const int*   __restrict__ mask_gt,
    int* __restrict__ fb_cnt,
    int* __restrict__ fb_idx)
{
    int bg = blockIdx.x;
    const float* gbb = gt_bboxes + (size_t)bg * 5;
    double cx = gbb[0], cy = gbb[1], w = gbb[2], h = gbb[3];
    double th = gbb[4];
    double ct = cos(-th), st = sin(-th);
    int tid = threadIdx.x;

    int cnt = 0;
    double ld[MAXF]; int li[MAXF];
#pragma unroll
    for (int t = 0; t < MAXF; t++) { ld[t] = 1e300; li[t] = 0x7fffffff; }

    for (int a = tid; a < NA; a += 256) {
        double ax = anchor_points[a * 2], ay = anchor_points[a * 2 + 1];
        double cdx = ax - cx, cdy = ay - cy;
        double ldx = cdx * ct - cdy * st;
        double ldy = cdx * st + cdy * ct;
        if (fabs(ldx) < w * 1.5 && fabs(ldy) < h * 1.5) cnt++;
        double d = sqrt(cdx * cdx + cdy * cdy);
        double cv = d; int ci = a;
#pragma unroll
        for (int p = 0; p < MAXF; p++) {
            bool better = (cv < ld[p]) || (cv == ld[p] && ci < li[p]);
            double tv = ld[p]; int ti = li[p];
            if (better) { ld[p] = cv; li[p] = ci; cv = tv; ci = ti; }
        }
    }

    __shared__ int    scnt[256];
    __shared__ double Ld[MAXF][256];
    __shared__ int    Lidx[MAXF][256];
    __shared__ double sv[256];
    __shared__ int    si[256];
    __shared__ int    win[MAXF];

    scnt[tid] = cnt;
#pragma unroll
    for (int t = 0; t < MAXF; t++) { Ld[t][tid] = ld[t]; Lidx[t][tid] = li[t]; }
    __syncthreads();
    for (int s2 = 128; s2 > 0; s2 >>= 1) {
        if (tid < s2) scnt[tid] += scnt[tid + s2];
        __syncthreads();
    }

    int ptr = 0;
    for (int j = 0; j < MAXF; j++) {
        double hv = (ptr < MAXF) ? Ld[ptr][tid] : 1e300;
        int    hi = (ptr < MAXF) ? Lidx[ptr][tid] : 0x7fffffff;
        sv[tid] = hv; si[tid] = hi;
        __syncthreads();
        for (int s2 = 128; s2 > 0; s2 >>= 1) {
            if (tid < s2) {
                bool better = (sv[tid + s2] < sv[tid]) ||
                              (sv[tid + s2] == sv[tid] && si[tid + s2] < si[tid]);
                if (better) { sv[tid] = sv[tid + s2]; si[tid] = si[tid + s2]; }
            }
            __syncthreads();
        }
        int Wi = si[0];
        if (tid == 0) win[j] = Wi;
        __syncthreads();
        if (ptr < MAXF && hi == Wi) ptr++;
    }

    if (tid == 0) {
        int m = mask_gt[bg];
        double area = (double)gbb[2] * (double)gbb[3];
        int total = scnt[0];
        int k = 0;
        if (m > 0 && area < 0.01 && total == 0) k = (area < 0.002) ? 5 : 3;
        fb_cnt[bg] = k;
        for (int j = 0; j < MAXF; j++) fb_idx[bg * MAXF + j] = win[j];
    }
}

// ---------- K2: per-gt top-10, dynamic_k, pos bits, am_max ----------

__global__ __launch_bounds__(256) void k_topk(
    const float* __restrict__ pred_scores,
    const float* __restrict__ pred_bboxes,
    const float* __restrict__ anchor_points,
    const int*   __restrict__ gt_labels,
    const float* __restrict__ gt_bboxes,
    const int*   __restrict__ mask_gt,
    const int*   __restrict__ fb_cnt,
    const int*   __restrict__ fb_idx,
    double* __restrict__ am_max,
    int* __restrict__ pos_mask)
{
    int bg = blockIdx.x;
    int b = bg / NG;
    int tid = threadIdx.x;
    int m = mask_gt[bg];
    if (m <= 0) {
        if (tid == 0) am_max[bg] = 0.0;
        return;
    }
    const float* gbb = gt_bboxes + (size_t)bg * 5;
    double cx = gbb[0], cy = gbb[1], w = gbb[2], h = gbb[3], th = gbb[4];
    double ct = cos(-th), st = sin(-th);
    double scale = sqrt(w * h);
    int lbl = gt_labels[bg];
    int fcnt = fb_cnt[bg];
    int fidx[MAXF];
#pragma unroll
    for (int t = 0; t < MAXF; t++) fidx[t] = fb_idx[bg * MAXF + t];

    double lv[KTOP]; int li2[KTOP];
#pragma unroll
    for (int t = 0; t < KTOP; t++) { lv[t] = -1.0; li2[t] = 0x7fffffff; }

    for (int a = tid; a < NA; a += 256) {
        double px = pred_bboxes[((size_t)b * NA + a) * 5 + 0];
        double py = pred_bboxes[((size_t)b * NA + a) * 5 + 1];
        double ax = anchor_points[a * 2], ay = anchor_points[a * 2 + 1];
        double sgm = sigmoid_clip((double)pred_scores[((size_t)b * NA + a) * NC + lbl]);
        bool fb = false;
#pragma unroll
        for (int t = 0; t < MAXF; t++) if (t < fcnt && fidx[t] == a) fb = true;
        double am, ov;
        metric_chain(sgm, px, py, ax, ay, cx, cy, ct, st, scale, w, h, fb, am, ov);
        (void)ov;
        double cv = am; int ci = a;
#pragma unroll
        for (int p = 0; p < KTOP; p++) {
            bool better = (cv > lv[p]) || (cv == lv[p] && ci < li2[p]);
            double tv = lv[p]; int ti = li2[p];
            if (better) { lv[p] = cv; li2[p] = ci; cv = tv; ci = ti; }
        }
    }

    __shared__ double Lv[KTOP][256];
    __shared__ int    Li[KTOP][256];
    __shared__ double sv[256];
    __shared__ int    si[256];
    __shared__ double wv_s[KTOP];
    __shared__ int    wi_s[KTOP];

#pragma unroll
    for (int t = 0; t < KTOP; t++) { Lv[t][tid] = lv[t]; Li[t][tid] = li2[t]; }
    __syncthreads();

    int ptr = 0;
    for (int j = 0; j < KTOP; j++) {
        double hv = (ptr < KTOP) ? Lv[ptr][tid] : -1.0;
        int    hi = (ptr < KTOP) ? Li[ptr][tid] : 0x7fffffff;
        sv[tid] = hv; si[tid] = hi;
        __syncthreads();
        for (int s2 = 128; s2 > 0; s2 >>= 1) {
            if (tid < s2) {
                bool better = (sv[tid + s2] > sv[tid]) ||
                              (sv[tid + s2] == sv[tid] && si[tid + s2] < si[tid]);
                if (better) { sv[tid] = sv[tid + s2]; si[tid] = si[tid + s2]; }
            }
            __syncthreads();
        }
        int Wi = si[0];
        if (tid == 0) { wv_s[j] = sv[0]; wi_s[j] = Wi; }
        __syncthreads();
        if (ptr < KTOP && hi == Wi) ptr++;
    }

    if (tid == 0) {
        am_max[bg] = wv_s[0];
        double ssum = 0.0;
        for (int j = 0; j < KTOP; j++) {
            int aW = wi_s[j];
            double px = pred_bboxes[((size_t)b * NA + aW) * 5 + 0];
            double py = pred_bboxes[((size_t)b * NA + aW) * 5 + 1];
            double dx = px - cx, dy = py - cy;
            double d = sqrt(dx * dx + dy * dy);
            double r = d / (scale + 1e-6);
            ssum += exp(-(r * r));
        }
        double rk = rint(ssum);
        rk = fmin(fmax(rk, 1.0), 10.0);
        for (int j = 0; j < KTOP; j++) {
            if (wv_s[j] > 1e-9 && (double)j < rk)
                atomicOr(&pos_mask[b * NA + wi_s[j]], 1);
        }
    }
}

// ---------- K3: per-anchor argmax + outputs ----------

__global__ __launch_bounds__(256) void k_final(
    const float* __restrict__ pred_scores,
    const float* __restrict__ pred_bboxes,
    const float* __restrict__ anchor_points,
    const int*   __restrict__ gt_labels,
    const float* __restrict__ gt_bboxes,
    const int*   __restrict__ mask_gt,
    const int*   __restrict__ fb_cnt,
    const int*   __restrict__ fb_idx,
    const double* __restrict__ am_max,
    const int*   __restrict__ pos_mask,
    float* __restrict__ out)
{
    __shared__ double s_cx[NG], s_cy[NG], s_ct[NG], s_st[NG], s_scale[NG], s_w[NG], s_h[NG], s_am[NG];
    __shared__ int s_lbl[NG], s_msk[NG], s_fcnt[NG];
    __shared__ int s_fidx[NG][MAXF];

    int b = blockIdx.y;
    int tid = threadIdx.x;
    if (tid < NG) {
        int g = tid, bg = b * NG + g;
        const float* gbb = gt_bboxes + (size_t)bg * 5;
        double th = gbb[4];
        s_cx[g] = gbb[0]; s_cy[g] = gbb[1]; s_w[g] = gbb[2]; s_h[g] = gbb[3];
        s_ct[g] = cos(-th); s_st[g] = sin(-th);
        s_scale[g] = sqrt((double)gbb[2] * (double)gbb[3]);
        s_am[g] = am_max[bg];
        s_lbl[g] = gt_labels[bg];
        s_msk[g] = mask_gt[bg];
        s_fcnt[g] = fb_cnt[bg];
        for (int t = 0; t < MAXF; t++) s_fidx[g][t] = fb_idx[bg * MAXF + t];
    }
    __syncthreads();

    int a = blockIdx.x * 256 + tid;
    if (a >= NA) return;

    double px = pred_bboxes[((size_t)b * NA + a) * 5 + 0];
    double py = pred_bboxes[((size_t)b * NA + a) * 5 + 1];
    double ax = anchor_points[a * 2], ay = anchor_points[a * 2 + 1];
    double sg0 = sigmoid_clip((double)pred_scores[((size_t)b * NA + a) * NC + 0]);
    double sg1 = sigmoid_clip((double)pred_scores[((size_t)b * NA + a) * NC + 1]);
    double sg2 = sigmoid_clip((double)pred_scores[((size_t)b * NA + a) * NC + 2]);
    double sg3 = sigmoid_clip((double)pred_scores[((size_t)b * NA + a) * NC + 3]);
    double sg4 = sigmoid_clip((double)pred_scores[((size_t)b * NA + a) * NC + 4]);

    double best = -1.0; int bestg = 0; double best_ov = 0.0;
    for (int g = 0; g < NG; g++) {
        int l = s_lbl[g];
        double sgm = (l == 0) ? sg0 : (l == 1) ? sg1 : (l == 2) ? sg2 : (l == 3) ? sg3 : sg4;
        bool fb = false;
        int fc = s_fcnt[g];
#pragma unroll
        for (int t = 0; t < MAXF; t++) if (t < fc && s_fidx[g][t] == a) fb = true;
        double am, ov;
        metric_chain(sgm, px, py, ax, ay, s_cx[g], s_cy[g], s_ct[g], s_st[g],
                     s_scale[g], s_w[g], s_h[g], fb, am, ov);
        double amm = (s_msk[g] > 0) ? am : 0.0;
        if (amm > best) { best = amm; bestg = g; best_ov = ov; }
    }

    int lbl = s_lbl[bestg];
    bool pos = pos_mask[b * NA + a] != 0;
    bool valid = (lbl >= 0 && lbl < NC) && pos;
    double raw = best / (s_am[bestg] + 1e-9) * best_ov;
    double soft = (raw > 0.0) ? sqrt(raw) : 0.0;

    size_t ba = (size_t)b * NA + a;
    out[ba] = (float)lbl;
    const float* gbb = gt_bboxes + ((size_t)b * NG + bestg) * 5;
    float* ob = out + (size_t)NB * NA + ba * 5;
    ob[0] = gbb[0]; ob[1] = gbb[1]; ob[2] = gbb[2]; ob[3] = gbb[3]; ob[4] = gbb[4];
    float* os = out + (size_t)NB * NA * 6 + ba * 5;
    float sval = valid ? (float)soft : 0.0f;
#pragma unroll
    for (int c = 0; c < NC; c++) os[c] = (c == lbl) ? sval : 0.0f;
    out[(size_t)NB * NA * 11 + ba] = pos ? 1.0f : 0.0f;
}

// ---------- launch ----------

extern "C" void kernel_launch(void* const* d_in, const int* in_sizes, int n_in,
                              void* d_out, int out_size, void* d_ws, size_t ws_size,
                              hipStream_t stream)
{
    const float* pred_scores   = (const float*)d_in[0];
    const float* pred_bboxes   = (const float*)d_in[1];
    const float* anchor_points = (const float*)d_in[2];
    const int*   gt_labels     = (const int*)d_in[3];
    const float* gt_bboxes     = (const float*)d_in[4];
    const int*   mask_gt       = (const int*)d_in[5];
    float* out = (float*)d_out;

    char* ws = (char*)d_ws;
    size_t off = 0;
    int* pos_mask = (int*)(ws + off);
    off += (size_t)NB * NA * sizeof(int);
    off = (off + 255) & ~(size_t)255;
    double* amax = (double*)(ws + off);
    off += (size_t)NB * NG * sizeof(double);
    off = (off + 255) & ~(size_t)255;
    int* fb_cnt = (int*)(ws + off);
    off += (size_t)NB * NG * sizeof(int);
    off = (off + 255) & ~(size_t)255;
    int* fb_idx = (int*)(ws + off);

    hipMemsetAsync(pos_mask, 0, (size_t)NB * NA * sizeof(int), stream);

    k_fallback<<<NB * NG, 256, 0, stream>>>(anchor_points, gt_bboxes, mask_gt, fb_cnt, fb_idx);
    k_topk<<<NB * NG, 256, 0, stream>>>(pred_scores, pred_bboxes, anchor_points, gt_labels,
                                        gt_bboxes, mask_gt, fb_cnt, fb_idx, amax, pos_mask);
    k_final<<<dim3((NA + 255) / 256, NB), 256, 0, stream>>>(
        pred_scores, pred_bboxes, anchor_points, gt_labels, gt_bboxes, mask_gt,
        fb_cnt, fb_idx, amax, pos_mask, out);
}

// Round 3
// 337.177 us; speedup vs baseline: 1.7442x; 1.7442x over previous
//
#include <hip/hip_runtime.h>
#include <math.h>

#define NB 16
#define NA 8400
#define NG 128
#define NC 5
#define KTOP 10
#define MAXF 5

// ---------- K0: per-(b,a,c) log(sigmoid_clip + EPS) table, f64 ----------

__global__ __launch_bounds__(256) void k_logsig(
    const float* __restrict__ pred_scores, double* __restrict__ table, int n)
{
    int i = blockIdx.x * 256 + threadIdx.x;
    if (i < n) {
        double x = (double)pred_scores[i];
        double s = 1.0 / (1.0 + exp(-x));
        s = fmin(fmax(s, 1e-9), 1.0);
        table[i] = log(s + 1e-9);
    }
}

// ---------- K1: merged per-gt fallback + top-10 + dynamic_k + pos bits + am_max ----------

__global__ __launch_bounds__(256) void k_assign(
    const float* __restrict__ pred_bboxes,
    const float* __restrict__ anchor_points,
    const int*   __restrict__ gt_labels,
    const float* __restrict__ gt_bboxes,
    const int*   __restrict__ mask_gt,
    const double* __restrict__ logsig,
    int* __restrict__ fb_cnt,
    int* __restrict__ fb_idx,
    double* __restrict__ am_max,
    int* __restrict__ pos_mask)
{
    int bg = blockIdx.x;
    int b = bg / NG;
    int tid = threadIdx.x;

    const float* gbb = gt_bboxes + (size_t)bg * 5;
    double cx = gbb[0], cy = gbb[1], w = gbb[2], h = gbb[3], th = gbb[4];
    double ct = cos(-th), st = sin(-th);
    int m = mask_gt[bg];
    double area = (double)gbb[2] * (double)gbb[3];

    // shared buffers (reused across phases)
    __shared__ double Sv[KTOP][256];
    __shared__ int    Si[KTOP][256];
    __shared__ double rv[256];
    __shared__ int    ri[256];
    __shared__ double wv_s[KTOP];
    __shared__ int    wi_s[KTOP];
    __shared__ int    s_icnt[256];
    __shared__ int    s_win[MAXF];
    __shared__ int    s_k;

    // ---- fallback phase (only when it can possibly matter) ----
    bool need_fb = (m > 0) && (area < 0.01);
    if (tid == 0) s_k = 0;
    if (need_fb) {
        int cnt = 0;
        double ld[MAXF]; int li[MAXF];
#pragma unroll
        for (int t = 0; t < MAXF; t++) { ld[t] = 1e300; li[t] = 0x7fffffff; }
        for (int a = tid; a < NA; a += 256) {
            double ax = anchor_points[a * 2], ay = anchor_points[a * 2 + 1];
            double cdx = ax - cx, cdy = ay - cy;
            double ldx = cdx * ct - cdy * st;
            double ldy = cdx * st + cdy * ct;
            if (fabs(ldx) < w * 1.5 && fabs(ldy) < h * 1.5) cnt++;
            double d = sqrt(cdx * cdx + cdy * cdy);
            double cv = d; int ci = a;
#pragma unroll
            for (int p = 0; p < MAXF; p++) {
                bool better = (cv < ld[p]) || (cv == ld[p] && ci < li[p]);
                double tv = ld[p]; int ti = li[p];
                if (better) { ld[p] = cv; li[p] = ci; cv = tv; ci = ti; }
            }
        }
        s_icnt[tid] = cnt;
#pragma unroll
        for (int t = 0; t < MAXF; t++) { Sv[t][tid] = ld[t]; Si[t][tid] = li[t]; }
        __syncthreads();
        for (int s2 = 128; s2 > 0; s2 >>= 1) {
            if (tid < s2) s_icnt[tid] += s_icnt[tid + s2];
            __syncthreads();
        }
        int ptr = 0;
        for (int j = 0; j < MAXF; j++) {
            double hv = (ptr < MAXF) ? Sv[ptr][tid] : 1e300;
            int    hi = (ptr < MAXF) ? Si[ptr][tid] : 0x7fffffff;
            rv[tid] = hv; ri[tid] = hi;
            __syncthreads();
            for (int s2 = 128; s2 > 0; s2 >>= 1) {
                if (tid < s2) {
                    bool better = (rv[tid + s2] < rv[tid]) ||
                                  (rv[tid + s2] == rv[tid] && ri[tid + s2] < ri[tid]);
                    if (better) { rv[tid] = rv[tid + s2]; ri[tid] = ri[tid + s2]; }
                }
                __syncthreads();
            }
            int Wi = ri[0];
            if (tid == 0) s_win[j] = Wi;
            __syncthreads();
            if (ptr < MAXF && hi == Wi) ptr++;
        }
        if (tid == 0) {
            int total = s_icnt[0];
            int k = 0;
            if (total == 0) k = (area < 0.002) ? 5 : 3;
            s_k = k;
            for (int j = 0; j < MAXF; j++) fb_idx[bg * MAXF + j] = s_win[j];
        }
        __syncthreads();
    }
    if (tid == 0) fb_cnt[bg] = s_k;

    if (m <= 0) {
        if (tid == 0) am_max[bg] = 0.0;
        return;
    }
    __syncthreads();

    double scale = sqrt(w * h);
    int lbl = gt_labels[bg];
    int fcnt = s_k;
    int fidx[MAXF];
#pragma unroll
    for (int t = 0; t < MAXF; t++) fidx[t] = need_fb ? s_win[t] : 0x7fffffff;

    // ---- top-10 phase (fused-exponent metric) ----
    double lv[KTOP]; int li2[KTOP];
#pragma unroll
    for (int t = 0; t < KTOP; t++) { lv[t] = -1.0; li2[t] = 0x7fffffff; }

    for (int a = tid; a < NA; a += 256) {
        double ax = anchor_points[a * 2], ay = anchor_points[a * 2 + 1];
        double cdx = ax - cx, cdy = ay - cy;
        double ldx = cdx * ct - cdy * st;
        double ldy = cdx * st + cdy * ct;
        bool inb = (fabs(ldx) < w * 1.5) && (fabs(ldy) < h * 1.5);
        bool fb = false;
#pragma unroll
        for (int t = 0; t < MAXF; t++) if (t < fcnt && fidx[t] == a) fb = true;
        double amm = 0.0;
        if (inb || fb) {
            double lgs = logsig[((size_t)b * NA + a) * NC + lbl];
            double px = pred_bboxes[((size_t)b * NA + a) * 5 + 0];
            double py = pred_bboxes[((size_t)b * NA + a) * 5 + 1];
            double dx = px - cx, dy = py - cy;
            double d  = sqrt(dx * dx + dy * dy);
            double r  = d / (scale + 1e-6);
            double e1 = exp(-(r * r));
            double L  = log(e1 + 1e-9);
            double cd = sqrt(cdx * cdx + cdy * cdy);
            double cr = cd / (scale * 1.5 + 1e-6);
            amm = exp(0.5 * lgs + 6.0 * L - cr * cr);
        }
        double cv = amm; int ci = a;
#pragma unroll
        for (int p = 0; p < KTOP; p++) {
            bool better = (cv > lv[p]) || (cv == lv[p] && ci < li2[p]);
            double tv = lv[p]; int ti = li2[p];
            if (better) { lv[p] = cv; li2[p] = ci; cv = tv; ci = ti; }
        }
    }

#pragma unroll
    for (int t = 0; t < KTOP; t++) { Sv[t][tid] = lv[t]; Si[t][tid] = li2[t]; }
    __syncthreads();

    int ptr = 0;
    for (int j = 0; j < KTOP; j++) {
        double hv = (ptr < KTOP) ? Sv[ptr][tid] : -1.0;
        int    hi = (ptr < KTOP) ? Si[ptr][tid] : 0x7fffffff;
        rv[tid] = hv; ri[tid] = hi;
        __syncthreads();
        for (int s2 = 128; s2 > 0; s2 >>= 1) {
            if (tid < s2) {
                bool better = (rv[tid + s2] > rv[tid]) ||
                              (rv[tid + s2] == rv[tid] && ri[tid + s2] < ri[tid]);
                if (better) { rv[tid] = rv[tid + s2]; ri[tid] = ri[tid + s2]; }
            }
            __syncthreads();
        }
        int Wi = ri[0];
        if (tid == 0) { wv_s[j] = rv[0]; wi_s[j] = Wi; }
        __syncthreads();
        if (ptr < KTOP && hi == Wi) ptr++;
    }

    if (tid == 0) {
        am_max[bg] = wv_s[0];
        double ssum = 0.0;
        for (int j = 0; j < KTOP; j++) {
            int aW = wi_s[j];
            double px = pred_bboxes[((size_t)b * NA + aW) * 5 + 0];
            double py = pred_bboxes[((size_t)b * NA + aW) * 5 + 1];
            double dx = px - cx, dy = py - cy;
            double d = sqrt(dx * dx + dy * dy);
            double r = d / (scale + 1e-6);
            ssum += exp(-(r * r));
        }
        double rk = rint(ssum);
        rk = fmin(fmax(rk, 1.0), 10.0);
        for (int j = 0; j < KTOP; j++) {
            if (wv_s[j] > 1e-9 && (double)j < rk)
                atomicOr(&pos_mask[b * NA + wi_s[j]], 1);
        }
    }
}

// ---------- K2: per-anchor argmax (g-sliced for occupancy) + outputs ----------

__global__ __launch_bounds__(256) void k_final(
    const float* __restrict__ pred_bboxes,
    const float* __restrict__ anchor_points,
    const int*   __restrict__ gt_labels,
    const float* __restrict__ gt_bboxes,
    const int*   __restrict__ mask_gt,
    const double* __restrict__ logsig,
    const int*   __restrict__ fb_cnt,
    const int*   __restrict__ fb_idx,
    const double* __restrict__ am_max,
    const int*   __restrict__ pos_mask,
    float* __restrict__ out)
{
    __shared__ double s_cx[NG], s_cy[NG], s_ct[NG], s_st[NG], s_scale[NG], s_w[NG], s_h[NG], s_am[NG];
    __shared__ int s_lbl[NG], s_msk[NG], s_fcnt[NG];
    __shared__ int s_fidx[NG][MAXF];
    __shared__ double mv[4][64];
    __shared__ int    mg[4][64];
    __shared__ double mo[4][64];

    int b = blockIdx.y;
    int tid = threadIdx.x;
    if (tid < NG) {
        int g = tid, bg = b * NG + g;
        const float* gbb = gt_bboxes + (size_t)bg * 5;
        double th = gbb[4];
        s_cx[g] = gbb[0]; s_cy[g] = gbb[1]; s_w[g] = gbb[2]; s_h[g] = gbb[3];
        s_ct[g] = cos(-th); s_st[g] = sin(-th);
        s_scale[g] = sqrt((double)gbb[2] * (double)gbb[3]);
        s_am[g] = am_max[bg];
        s_lbl[g] = gt_labels[bg];
        s_msk[g] = mask_gt[bg];
        s_fcnt[g] = fb_cnt[bg];
        for (int t = 0; t < MAXF; t++) s_fidx[g][t] = fb_idx[bg * MAXF + t];
    }
    __syncthreads();

    int al = tid & 63;
    int slice = tid >> 6;
    int a = blockIdx.x * 64 + al;

    double best = -1.0; int bestg = slice * 32; double bov = 0.0;
    if (a < NA) {
        double px = pred_bboxes[((size_t)b * NA + a) * 5 + 0];
        double py = pred_bboxes[((size_t)b * NA + a) * 5 + 1];
        double ax = anchor_points[a * 2], ay = anchor_points[a * 2 + 1];
        const double* lg = logsig + ((size_t)b * NA + a) * NC;
        double l0 = lg[0], l1 = lg[1], l2 = lg[2], l3 = lg[3], l4 = lg[4];

        int g0 = slice * 32;
        for (int g = g0; g < g0 + 32; g++) {
            int lbl = s_lbl[g];
            double lgs = (lbl == 0) ? l0 : (lbl == 1) ? l1 : (lbl == 2) ? l2 : (lbl == 3) ? l3 : l4;
            bool fb = false;
            int fc = s_fcnt[g];
#pragma unroll
            for (int t = 0; t < MAXF; t++) if (t < fc && s_fidx[g][t] == a) fb = true;
            double cdx = ax - s_cx[g], cdy = ay - s_cy[g];
            double ldx = cdx * s_ct[g] - cdy * s_st[g];
            double ldy = cdx * s_st[g] + cdy * s_ct[g];
            bool inb = (fabs(ldx) < s_w[g] * 1.5) && (fabs(ldy) < s_h[g] * 1.5);
            double amm = 0.0, e1 = 0.0;
            if ((inb || fb) && s_msk[g] > 0) {
                double dx = px - s_cx[g], dy = py - s_cy[g];
                double d = sqrt(dx * dx + dy * dy);
                double r = d / (s_scale[g] + 1e-6);
                e1 = exp(-(r * r));
                double L = log(e1 + 1e-9);
                double cd = sqrt(cdx * cdx + cdy * cdy);
                double cr = cd / (s_scale[g] * 1.5 + 1e-6);
                amm = exp(0.5 * lgs + 6.0 * L - cr * cr);
            }
            if (amm > best) { best = amm; bestg = g; bov = e1; }
        }
    }

    mv[slice][al] = best; mg[slice][al] = bestg; mo[slice][al] = bov;
    __syncthreads();

    if (tid < 64) {
        int a2 = blockIdx.x * 64 + tid;
        if (a2 < NA) {
            double B = mv[0][tid]; int G = mg[0][tid]; double OV = mo[0][tid];
#pragma unroll
            for (int s = 1; s < 4; s++) {
                if (mv[s][tid] > B) { B = mv[s][tid]; G = mg[s][tid]; OV = mo[s][tid]; }
            }
            int lbl = s_lbl[G];
            bool pos = pos_mask[b * NA + a2] != 0;
            bool valid = (lbl >= 0 && lbl < NC) && pos;
            double raw = B / (s_am[G] + 1e-9) * OV;
            double soft = (raw > 0.0) ? sqrt(raw) : 0.0;

            size_t ba = (size_t)b * NA + a2;
            out[ba] = (float)lbl;
            const float* gb2 = gt_bboxes + ((size_t)b * NG + G) * 5;
            float* ob = out + (size_t)NB * NA + ba * 5;
            ob[0] = gb2[0]; ob[1] = gb2[1]; ob[2] = gb2[2]; ob[3] = gb2[3]; ob[4] = gb2[4];
            float* os = out + (size_t)NB * NA * 6 + ba * 5;
            float sval = valid ? (float)soft : 0.0f;
#pragma unroll
            for (int c = 0; c < NC; c++) os[c] = (c == lbl) ? sval : 0.0f;
            out[(size_t)NB * NA * 11 + ba] = pos ? 1.0f : 0.0f;
        }
    }
}

// ---------- launch ----------

extern "C" void kernel_launch(void* const* d_in, const int* in_sizes, int n_in,
                              void* d_out, int out_size, void* d_ws, size_t ws_size,
                              hipStream_t stream)
{
    const float* pred_scores   = (const float*)d_in[0];
    const float* pred_bboxes   = (const float*)d_in[1];
    const float* anchor_points = (const float*)d_in[2];
    const int*   gt_labels     = (const int*)d_in[3];
    const float* gt_bboxes     = (const float*)d_in[4];
    const int*   mask_gt       = (const int*)d_in[5];
    float* out = (float*)d_out;

    char* ws = (char*)d_ws;
    size_t off = 0;
    int* pos_mask = (int*)(ws + off);
    off += (size_t)NB * NA * sizeof(int);
    off = (off + 255) & ~(size_t)255;
    double* amax = (double*)(ws + off);
    off += (size_t)NB * NG * sizeof(double);
    off = (off + 255) & ~(size_t)255;
    int* fb_cnt = (int*)(ws + off);
    off += (size_t)NB * NG * sizeof(int);
    off = (off + 255) & ~(size_t)255;
    int* fb_idx = (int*)(ws + off);
    off += (size_t)NB * NG * MAXF * sizeof(int);
    off = (off + 255) & ~(size_t)255;
    double* logsig = (double*)(ws + off);

    hipMemsetAsync(pos_mask, 0, (size_t)NB * NA * sizeof(int), stream);

    int nls = NB * NA * NC;
    k_logsig<<<(nls + 255) / 256, 256, 0, stream>>>(pred_scores, logsig, nls);
    k_assign<<<NB * NG, 256, 0, stream>>>(pred_bboxes, anchor_points, gt_labels,
                                          gt_bboxes, mask_gt, logsig,
                                          fb_cnt, fb_idx, amax, pos_mask);
    k_final<<<dim3((NA + 63) / 64, NB), 256, 0, stream>>>(
        pred_bboxes, anchor_points, gt_labels, gt_bboxes, mask_gt, logsig,
        fb_cnt, fb_idx, amax, pos_mask, out);
}